// Round 1
// baseline (1265.889 us; speedup 1.0000x reference)
//
#include <hip/hip_runtime.h>

#define NDRUG 20000
#define NTGT  20000
#define NN    40000
#define NE    500000
#define DDIM  128
#define CAP   256

// ---------------- GEMM: C[M,128] = A[M,K] @ W[K,128] (+ bias) ----------------
// BM=32, BN=128, BK=32, 256 threads, 4x4 micro-tile per thread.
__global__ __launch_bounds__(256)
void gemm_rm(const float* __restrict__ A, const float* __restrict__ W,
             const float* __restrict__ bias, float* __restrict__ C,
             int M, int K) {
  __shared__ float As[32][33];
  __shared__ float Ws[32][128];
  const int t  = threadIdx.x;
  const int bm = blockIdx.x * 32;
  const int tx = t & 31;   // cols 4*tx..4*tx+3
  const int ty = t >> 5;   // rows 4*ty..4*ty+3
  float acc[4][4] = {};
  for (int kk = 0; kk < K; kk += 32) {
    {
      const int r = t >> 3, k0 = (t & 7) << 2;
      const float4 v = *(const float4*)(A + (size_t)(bm + r) * K + kk + k0);
      As[r][k0 + 0] = v.x; As[r][k0 + 1] = v.y; As[r][k0 + 2] = v.z; As[r][k0 + 3] = v.w;
    }
    {
      const int c4 = (t & 31) << 2, kr = t >> 5;
#pragma unroll
      for (int i = 0; i < 4; ++i) {
        const int k = kr + (i << 3);
        *(float4*)&Ws[k][c4] = *(const float4*)(W + (size_t)(kk + k) * DDIM + c4);
      }
    }
    __syncthreads();
#pragma unroll
    for (int k = 0; k < 32; ++k) {
      const float4 wv = *(const float4*)&Ws[k][tx << 2];
#pragma unroll
      for (int i = 0; i < 4; ++i) {
        const float a = As[(ty << 2) + i][k];
        acc[i][0] += a * wv.x; acc[i][1] += a * wv.y;
        acc[i][2] += a * wv.z; acc[i][3] += a * wv.w;
      }
    }
    __syncthreads();
  }
  float4 bv = {0.f, 0.f, 0.f, 0.f};
  if (bias) bv = *(const float4*)(bias + (tx << 2));
#pragma unroll
  for (int i = 0; i < 4; ++i) {
    const int row = bm + (ty << 2) + i;
    float4 o = { acc[i][0] + bv.x, acc[i][1] + bv.y, acc[i][2] + bv.z, acc[i][3] + bv.w };
    *(float4*)(C + (size_t)row * DDIM + (tx << 2)) = o;
  }
}

// ------------- edge bias for BOTH layers in one pass over edge_attr -------------
__global__ __launch_bounds__(256)
void edge_bias_kernel(const float* __restrict__ ea, const float* __restrict__ ae0,
                      const float* __restrict__ ae1, float* __restrict__ b0,
                      float* __restrict__ b1) {
  const int wave = threadIdx.x >> 6, lane = threadIdx.x & 63;
  const int e = blockIdx.x * 4 + wave;
  if (e >= NE) return;
  const float* p = ea + (size_t)e * DDIM;
  const float v0 = p[lane], v1 = p[lane + 64];
  float s0 = v0 * ae0[lane] + v1 * ae0[lane + 64];
  float s1 = v0 * ae1[lane] + v1 * ae1[lane + 64];
#pragma unroll
  for (int o = 32; o; o >>= 1) { s0 += __shfl_xor(s0, o); s1 += __shfl_xor(s1, o); }
  if (lane == 0) { b0[e] = s0; b1[e] = s1; }
}

// ------------- per-node s = hp.a_src, d = hp.a_dst -------------
__global__ __launch_bounds__(256)
void sd_kernel(const float* __restrict__ hp, const float* __restrict__ asrc,
               const float* __restrict__ adst, float* __restrict__ s,
               float* __restrict__ d) {
  const int wave = threadIdx.x >> 6, lane = threadIdx.x & 63;
  const int n = blockIdx.x * 4 + wave;
  if (n >= NN) return;
  const float* p = hp + (size_t)n * DDIM;
  const float v0 = p[lane], v1 = p[lane + 64];
  float sv = v0 * asrc[lane] + v1 * asrc[lane + 64];
  float dv = v0 * adst[lane] + v1 * adst[lane + 64];
#pragma unroll
  for (int o = 32; o; o >>= 1) { sv += __shfl_xor(sv, o); dv += __shfl_xor(dv, o); }
  if (lane == 0) { s[n] = sv; d[n] = dv; }
}

// ------------- CSR build -------------
__global__ void count_kernel(const int* __restrict__ dst, int* __restrict__ counts) {
  for (int e = blockIdx.x * blockDim.x + threadIdx.x; e < NE; e += gridDim.x * blockDim.x)
    atomicAdd(&counts[dst[e]], 1);
}

__global__ __launch_bounds__(1024)
void scan_kernel(const int* __restrict__ counts, int* __restrict__ offs,
                 int* __restrict__ cursor) {
  __shared__ int part[1024];
  const int t = threadIdx.x;
  const int CH = 40;  // ceil(40000/1024)
  const int base = t * CH;
  const int lim = min(base + CH, NN);
  int sum = 0;
  for (int i = base; i < lim; ++i) sum += counts[i];
  part[t] = sum;
  __syncthreads();
  for (int o = 1; o < 1024; o <<= 1) {
    const int v = (t >= o) ? part[t - o] : 0;
    __syncthreads();
    part[t] += v;
    __syncthreads();
  }
  int run = (t == 0) ? 0 : part[t - 1];
  for (int i = base; i < lim; ++i) { offs[i] = run; cursor[i] = run; run += counts[i]; }
  if (t == 1023) offs[NN] = part[1023];
}

__global__ void fill_kernel(const int* __restrict__ src, const int* __restrict__ dst,
                            int* __restrict__ cursor, int* __restrict__ csrc,
                            int* __restrict__ ceid) {
  for (int e = blockIdx.x * blockDim.x + threadIdx.x; e < NE; e += gridDim.x * blockDim.x) {
    const int p = atomicAdd(&cursor[dst[e]], 1);
    csrc[p] = src[e];
    if (ceid) ceid[p] = e;
  }
}

// ------------- GAT per-dst aggregation: one wave per node -------------
__global__ __launch_bounds__(256)
void gat_aggregate(const int* __restrict__ offs, const int* __restrict__ csrc,
                   const int* __restrict__ ceid, const float* __restrict__ ebias,
                   const float* __restrict__ s, const float* __restrict__ dv,
                   const float* __restrict__ hp, float* __restrict__ outp,
                   int node_begin, int accumulate) {
  __shared__ float exbuf[4][CAP];
  __shared__ int   srcbuf[4][CAP];
  const int wave = threadIdx.x >> 6, lane = threadIdx.x & 63;
  const int node = node_begin + blockIdx.x * 4 + wave;
  const int beg = offs[node];
  int cnt = offs[node + 1] - beg;
  if (cnt > CAP) cnt = CAP;  // P(Poisson(25) > 256) ~ 0
  const int c0 = lane, c1 = lane + 64;
  float* orow = outp + (size_t)node * DDIM;
  if (cnt == 0) {
    if (!accumulate) { orow[c0] = 0.f; orow[c1] = 0.f; }
    return;
  }
  const float dn = dv[node];
  float m = -1e30f;
  for (int i = lane; i < cnt; i += 64) {
    const int sn = csrc[beg + i];
    float logit = s[sn] + dn;
    if (ebias) logit += ebias[ceid[beg + i]];
    const float e = logit >= 0.f ? logit : 0.2f * logit;
    exbuf[wave][i] = e;
    srcbuf[wave][i] = sn;
    m = fmaxf(m, e);
  }
#pragma unroll
  for (int o = 32; o; o >>= 1) m = fmaxf(m, __shfl_xor(m, o));
  float ssum = 0.f;
  for (int i = lane; i < cnt; i += 64) {
    const float ex = __expf(exbuf[wave][i] - m);
    exbuf[wave][i] = ex;
    ssum += ex;
  }
#pragma unroll
  for (int o = 32; o; o >>= 1) ssum += __shfl_xor(ssum, o);
  const float inv = 1.f / (ssum + 1e-16f);
  __threadfence_block();  // make all lanes' exbuf/srcbuf writes visible wave-wide
  float n0 = 0.f, n1 = 0.f;
  for (int i = 0; i < cnt; ++i) {
    const float w = exbuf[wave][i];
    const float* hr = hp + (size_t)srcbuf[wave][i] * DDIM;
    n0 += w * hr[c0];
    n1 += w * hr[c1];
  }
  float v0 = n0 * inv, v1 = n1 * inv;
  v0 = (v0 > 0.f ? v0 : expm1f(v0)) * (1.f / 3.f);
  v1 = (v1 > 0.f ? v1 : expm1f(v1)) * (1.f / 3.f);
  if (accumulate) { orow[c0] += v0; orow[c1] += v1; }
  else            { orow[c0] = v0;  orow[c1] = v1; }
}

extern "C" void kernel_launch(void* const* d_in, const int* in_sizes, int n_in,
                              void* d_out, int out_size, void* d_ws, size_t ws_size,
                              hipStream_t stream) {
  const float* x_drug    = (const float*)d_in[0];
  const float* x_target  = (const float*)d_in[1];
  const float* W_drug    = (const float*)d_in[2];
  const float* b_drug    = (const float*)d_in[3];
  const float* W_target  = (const float*)d_in[4];
  const float* b_target  = (const float*)d_in[5];
  const float* W_gat     = (const float*)d_in[6];
  const float* a_src     = (const float*)d_in[7];
  const float* a_dst     = (const float*)d_in[8];
  const float* a_edge    = (const float*)d_in[9];
  const float* edge_attr = (const float*)d_in[10];
  const int*   e_dd      = (const int*)d_in[11];
  const int*   e_dt      = (const int*)d_in[12];
  const int*   e_tt      = (const int*)d_in[13];
  float* out = (float*)d_out;

  char* ws = (char*)d_ws;
  size_t off = 0;
  auto alloc = [&](size_t b) -> void* {
    void* p = ws + off;
    off += (b + 255) & ~(size_t)255;
    return p;
  };
  float* hA    = (float*)alloc((size_t)NN * DDIM * 4);
  float* hB    = (float*)alloc((size_t)NN * DDIM * 4);
  float* hp    = (float*)alloc((size_t)NN * DDIM * 4);
  float* sbuf  = (float*)alloc((size_t)NN * 4);
  float* dbuf  = (float*)alloc((size_t)NN * 4);
  float* bias0 = (float*)alloc((size_t)NE * 4);
  float* bias1 = (float*)alloc((size_t)NE * 4);
  int* counts  = (int*)alloc((size_t)3 * NN * 4);
  int* offs0   = (int*)alloc((size_t)(NN + 1) * 4);
  int* offs1   = (int*)alloc((size_t)(NN + 1) * 4);
  int* offs2   = (int*)alloc((size_t)(NN + 1) * 4);
  int* cur0    = (int*)alloc((size_t)(NN + 1) * 4);
  int* cur1    = (int*)alloc((size_t)(NN + 1) * 4);
  int* cur2    = (int*)alloc((size_t)(NN + 1) * 4);
  int* csrc0   = (int*)alloc((size_t)NE * 4);
  int* csrc1   = (int*)alloc((size_t)NE * 4);
  int* csrc2   = (int*)alloc((size_t)NE * 4);
  int* ceid0   = (int*)alloc((size_t)NE * 4);

  // 1) input projections -> hA [40000,128]
  gemm_rm<<<NDRUG / 32, 256, 0, stream>>>(x_drug, W_drug, b_drug, hA, NDRUG, 2048);
  gemm_rm<<<NTGT / 32, 256, 0, stream>>>(x_target, W_target, b_target,
                                         hA + (size_t)NDRUG * DDIM, NTGT, 1280);
  // 2) edge biases for both layers, one pass over 256MB edge_attr
  edge_bias_kernel<<<NE / 4, 256, 0, stream>>>(edge_attr, a_edge, a_edge + DDIM,
                                               bias0, bias1);
  // 3) CSR (by dst) for the 3 relations; reused by both layers
  hipMemsetAsync(counts, 0, (size_t)3 * NN * 4, stream);
  count_kernel<<<512, 256, 0, stream>>>(e_dd + NE, counts);
  count_kernel<<<512, 256, 0, stream>>>(e_dt + NE, counts + NN);
  count_kernel<<<512, 256, 0, stream>>>(e_tt + NE, counts + 2 * NN);
  scan_kernel<<<1, 1024, 0, stream>>>(counts, offs0, cur0);
  scan_kernel<<<1, 1024, 0, stream>>>(counts + NN, offs1, cur1);
  scan_kernel<<<1, 1024, 0, stream>>>(counts + 2 * NN, offs2, cur2);
  fill_kernel<<<512, 256, 0, stream>>>(e_dd, e_dd + NE, cur0, csrc0, ceid0);
  fill_kernel<<<512, 256, 0, stream>>>(e_dt, e_dt + NE, cur1, csrc1, nullptr);
  fill_kernel<<<512, 256, 0, stream>>>(e_tt, e_tt + NE, cur2, csrc2, nullptr);

  // 4) two GAT layers
  for (int l = 0; l < 2; ++l) {
    const float* hin  = (l == 0) ? hA : hB;
    float*       hout = (l == 0) ? hB : out;
    const float* lbias = (l == 0) ? bias0 : bias1;
    for (int r = 0; r < 3; ++r) {
      const float* Wg = W_gat + (size_t)(l * 3 + r) * DDIM * DDIM;
      const float* as = a_src + (size_t)(l * 3 + r) * DDIM;
      const float* ad = a_dst + (size_t)(l * 3 + r) * DDIM;
      gemm_rm<<<NN / 32, 256, 0, stream>>>(hin, Wg, nullptr, hp, NN, DDIM);
      sd_kernel<<<NN / 4, 256, 0, stream>>>(hp, as, ad, sbuf, dbuf);
      if (r == 0)        // drug->drug: writes drug rows (x2=x3=0 there)
        gat_aggregate<<<NDRUG / 4, 256, 0, stream>>>(offs0, csrc0, ceid0, lbias,
                                                     sbuf, dbuf, hp, hout, 0, 0);
      else if (r == 1)   // drug->target: writes target rows
        gat_aggregate<<<NTGT / 4, 256, 0, stream>>>(offs1, csrc1, nullptr, nullptr,
                                                    sbuf, dbuf, hp, hout, NDRUG, 0);
      else               // target->target: accumulates into target rows
        gat_aggregate<<<NTGT / 4, 256, 0, stream>>>(offs2, csrc2, nullptr, nullptr,
                                                    sbuf, dbuf, hp, hout, NDRUG, 1);
    }
  }
}

// Round 3
// 1030.917 us; speedup vs baseline: 1.2279x; 1.2279x over previous
//
#include <hip/hip_runtime.h>

#define NDRUG 20000
#define NTGT  20000
#define NN    40000
#define NE    500000
#define DDIM  128
#define CAP   256

typedef __attribute__((ext_vector_type(4))) float f32x4;
typedef __attribute__((ext_vector_type(8))) short s16x8;
typedef __attribute__((ext_vector_type(4))) short s16x4;

__device__ inline unsigned short bf_rn(float x) {
  unsigned u = __float_as_uint(x);
  return (unsigned short)((u + 0x7FFFu + ((u >> 16) & 1u)) >> 16);
}
__device__ inline float bf_f(unsigned short h) {
  return __uint_as_float(((unsigned)h) << 16);
}

// ------- one-time weight prep: W [K][128] fp32 -> Wt_hi/Wt_lo [128][K] bf16 -------
__global__ void prep_w(const float* __restrict__ W, short* __restrict__ hi,
                       short* __restrict__ lo, int K) {
  const int idx = blockIdx.x * blockDim.x + threadIdx.x;
  if (idx >= K * 128) return;
  const int k = idx >> 7, c = idx & 127;
  const float x = W[idx];
  const unsigned short h = bf_rn(x);
  hi[(size_t)c * K + k] = (short)h;
  lo[(size_t)c * K + k] = (short)bf_rn(x - bf_f(h));
}

// ---------------- MFMA split-bf16 GEMM ----------------
// C[:, col_off + 0..128) = A[M,K] @ W  (+bias), LDC given.
// blockIdx.y = relation: selects Wt_(hi/lo) + rel*128*K, col_off = rel*128.
// BM=64, BN=128, BK=32, 256 threads, 4 waves each computing 32x64.
__global__ __launch_bounds__(256)
void gemm_mfma(const float* __restrict__ A, const short* __restrict__ WtH,
               const short* __restrict__ WtL, const float* __restrict__ bias,
               float* __restrict__ C, int M, int K, int LDC) {
  const int rel = blockIdx.y;
  WtH += (size_t)rel * 128 * K;
  WtL += (size_t)rel * 128 * K;
  const int col_off = rel * 128;

  __shared__ __align__(16) short Ah[64][40];
  __shared__ __align__(16) short Al[64][40];
  __shared__ __align__(16) short Bh[128][40];
  __shared__ __align__(16) short Bl[128][40];

  const int t = threadIdx.x;
  const int bm = blockIdx.x * 64;
  const int wave = t >> 6, lane = t & 63;
  const int wr = (wave >> 1) * 32, wc = (wave & 1) * 64;
  const int lr = lane & 15, kg = lane >> 4;

  f32x4 acc[2][4] = {};

  for (int kk = 0; kk < K; kk += 32) {
    // stage A 64x32 fp32 -> bf16 hi/lo  (32 rows x 8 col-groups x 2 iters)
    {
      const int r = t >> 3;
      const int k0 = (t & 7) << 2;
#pragma unroll
      for (int i = 0; i < 2; ++i) {
        const int row = r + i * 32;
        int grow = bm + row; if (grow >= M) grow = M - 1;
        const float4 v = *(const float4*)(A + (size_t)grow * K + kk + k0);
        const float xs[4] = {v.x, v.y, v.z, v.w};
        s16x4 h4, l4;
#pragma unroll
        for (int j = 0; j < 4; ++j) {
          const unsigned short hh = bf_rn(xs[j]);
          h4[j] = (short)hh;
          l4[j] = (short)bf_rn(xs[j] - bf_f(hh));
        }
        *(s16x4*)&Ah[row][k0] = h4;
        *(s16x4*)&Al[row][k0] = l4;
      }
    }
    // stage B: Wt rows [128][kk..kk+32) bf16 (pre-split).
    // 2 threads per row; each thread stages 16 shorts (two s16x8) per buffer.
    {
      const int c = t >> 1, o = (t & 1) * 16;
      const size_t boff = (size_t)c * K + kk + o;
      *(s16x8*)&Bh[c][o]     = *(const s16x8*)(WtH + boff);
      *(s16x8*)&Bh[c][o + 8] = *(const s16x8*)(WtH + boff + 8);
      *(s16x8*)&Bl[c][o]     = *(const s16x8*)(WtL + boff);
      *(s16x8*)&Bl[c][o + 8] = *(const s16x8*)(WtL + boff + 8);
    }
    __syncthreads();

    s16x8 ah[2], al[2], bh[4], bl[4];
#pragma unroll
    for (int m = 0; m < 2; ++m) {
      ah[m] = *(const s16x8*)&Ah[wr + m * 16 + lr][kg * 8];
      al[m] = *(const s16x8*)&Al[wr + m * 16 + lr][kg * 8];
    }
#pragma unroll
    for (int n = 0; n < 4; ++n) {
      bh[n] = *(const s16x8*)&Bh[wc + n * 16 + lr][kg * 8];
      bl[n] = *(const s16x8*)&Bl[wc + n * 16 + lr][kg * 8];
    }
#pragma unroll
    for (int m = 0; m < 2; ++m)
#pragma unroll
      for (int n = 0; n < 4; ++n) {
        acc[m][n] = __builtin_amdgcn_mfma_f32_16x16x32_bf16(ah[m], bh[n], acc[m][n], 0, 0, 0);
        acc[m][n] = __builtin_amdgcn_mfma_f32_16x16x32_bf16(ah[m], bl[n], acc[m][n], 0, 0, 0);
        acc[m][n] = __builtin_amdgcn_mfma_f32_16x16x32_bf16(al[m], bh[n], acc[m][n], 0, 0, 0);
      }
    __syncthreads();
  }

  // epilogue: D layout row=(lane>>4)*4+reg, col=lane&15
#pragma unroll
  for (int n = 0; n < 4; ++n) {
    const int lcol = wc + n * 16 + lr;
    const float bv = bias ? bias[lcol] : 0.f;
    const int col = col_off + lcol;
#pragma unroll
    for (int m = 0; m < 2; ++m) {
#pragma unroll
      for (int r = 0; r < 4; ++r) {
        const int row = bm + wr + m * 16 + kg * 4 + r;
        if (row < M) C[(size_t)row * LDC + col] = acc[m][n][r] + bv;
      }
    }
  }
}

// ------------- edge bias for BOTH layers in one pass over edge_attr -------------
__global__ __launch_bounds__(256)
void edge_bias_kernel(const float* __restrict__ ea, const float* __restrict__ ae0,
                      const float* __restrict__ ae1, float* __restrict__ b0,
                      float* __restrict__ b1) {
  const int wave = threadIdx.x >> 6, lane = threadIdx.x & 63;
  const int e = blockIdx.x * 4 + wave;
  if (e >= NE) return;
  const float* p = ea + (size_t)e * DDIM;
  const float v0 = p[lane], v1 = p[lane + 64];
  float s0 = v0 * ae0[lane] + v1 * ae0[lane + 64];
  float s1 = v0 * ae1[lane] + v1 * ae1[lane + 64];
#pragma unroll
  for (int o = 32; o; o >>= 1) { s0 += __shfl_xor(s0, o); s1 += __shfl_xor(s1, o); }
  if (lane == 0) { b0[e] = s0; b1[e] = s1; }
}

// ------------- per-node s = hp.a_src, d = hp.a_dst -------------
__global__ __launch_bounds__(256)
void sd_kernel(const float* __restrict__ hp, int stride, const float* __restrict__ asrc,
               const float* __restrict__ adst, float* __restrict__ s,
               float* __restrict__ d) {
  const int wave = threadIdx.x >> 6, lane = threadIdx.x & 63;
  const int n = blockIdx.x * 4 + wave;
  if (n >= NN) return;
  const float* p = hp + (size_t)n * stride;
  const float v0 = p[lane], v1 = p[lane + 64];
  float sv = v0 * asrc[lane] + v1 * asrc[lane + 64];
  float dv = v0 * adst[lane] + v1 * adst[lane + 64];
#pragma unroll
  for (int o = 32; o; o >>= 1) { sv += __shfl_xor(sv, o); dv += __shfl_xor(dv, o); }
  if (lane == 0) { s[n] = sv; d[n] = dv; }
}

// ------------- CSR build -------------
__global__ void count_kernel(const int* __restrict__ dst, int* __restrict__ counts) {
  for (int e = blockIdx.x * blockDim.x + threadIdx.x; e < NE; e += gridDim.x * blockDim.x)
    atomicAdd(&counts[dst[e]], 1);
}

__global__ __launch_bounds__(1024)
void scan_kernel(const int* __restrict__ counts, int* __restrict__ offs,
                 int* __restrict__ cursor) {
  __shared__ int part[1024];
  const int t = threadIdx.x;
  const int CH = 40;
  const int base = t * CH;
  const int lim = min(base + CH, NN);
  int sum = 0;
  for (int i = base; i < lim; ++i) sum += counts[i];
  part[t] = sum;
  __syncthreads();
  for (int o = 1; o < 1024; o <<= 1) {
    const int v = (t >= o) ? part[t - o] : 0;
    __syncthreads();
    part[t] += v;
    __syncthreads();
  }
  int run = (t == 0) ? 0 : part[t - 1];
  for (int i = base; i < lim; ++i) { offs[i] = run; cursor[i] = run; run += counts[i]; }
  if (t == 1023) offs[NN] = part[1023];
}

__global__ void fill_kernel(const int* __restrict__ src, const int* __restrict__ dst,
                            int* __restrict__ cursor, int* __restrict__ csrc,
                            int* __restrict__ ceid) {
  for (int e = blockIdx.x * blockDim.x + threadIdx.x; e < NE; e += gridDim.x * blockDim.x) {
    const int p = atomicAdd(&cursor[dst[e]], 1);
    csrc[p] = src[e];
    if (ceid) ceid[p] = e;
  }
}

// ------------- GAT per-dst aggregation: one wave per node -------------
__global__ __launch_bounds__(256)
void gat_aggregate(const int* __restrict__ offs, const int* __restrict__ csrc,
                   const int* __restrict__ ceid, const float* __restrict__ ebias,
                   const float* __restrict__ s, const float* __restrict__ dv,
                   const float* __restrict__ hp, int stride, float* __restrict__ outp,
                   int node_begin, int accumulate) {
  __shared__ float exbuf[4][CAP];
  __shared__ int   srcbuf[4][CAP];
  const int wave = threadIdx.x >> 6, lane = threadIdx.x & 63;
  const int node = node_begin + blockIdx.x * 4 + wave;
  const int beg = offs[node];
  int cnt = offs[node + 1] - beg;
  if (cnt > CAP) cnt = CAP;
  const int c0 = lane, c1 = lane + 64;
  float* orow = outp + (size_t)node * DDIM;
  if (cnt == 0) {
    if (!accumulate) { orow[c0] = 0.f; orow[c1] = 0.f; }
    return;
  }
  const float dn = dv[node];
  float m = -1e30f;
  for (int i = lane; i < cnt; i += 64) {
    const int sn = csrc[beg + i];
    float logit = s[sn] + dn;
    if (ebias) logit += ebias[ceid[beg + i]];
    const float e = logit >= 0.f ? logit : 0.2f * logit;
    exbuf[wave][i] = e;
    srcbuf[wave][i] = sn;
    m = fmaxf(m, e);
  }
#pragma unroll
  for (int o = 32; o; o >>= 1) m = fmaxf(m, __shfl_xor(m, o));
  float ssum = 0.f;
  for (int i = lane; i < cnt; i += 64) {
    const float ex = __expf(exbuf[wave][i] - m);
    exbuf[wave][i] = ex;
    ssum += ex;
  }
#pragma unroll
  for (int o = 32; o; o >>= 1) ssum += __shfl_xor(ssum, o);
  const float inv = 1.f / (ssum + 1e-16f);
  __threadfence_block();
  float n0 = 0.f, n1 = 0.f;
  for (int i = 0; i < cnt; ++i) {
    const float w = exbuf[wave][i];
    const float* hr = hp + (size_t)srcbuf[wave][i] * stride;
    n0 += w * hr[c0];
    n1 += w * hr[c1];
  }
  float v0 = n0 * inv, v1 = n1 * inv;
  v0 = (v0 > 0.f ? v0 : expm1f(v0)) * (1.f / 3.f);
  v1 = (v1 > 0.f ? v1 : expm1f(v1)) * (1.f / 3.f);
  if (accumulate) { orow[c0] += v0; orow[c1] += v1; }
  else            { orow[c0] = v0;  orow[c1] = v1; }
}

extern "C" void kernel_launch(void* const* d_in, const int* in_sizes, int n_in,
                              void* d_out, int out_size, void* d_ws, size_t ws_size,
                              hipStream_t stream) {
  const float* x_drug    = (const float*)d_in[0];
  const float* x_target  = (const float*)d_in[1];
  const float* W_drug    = (const float*)d_in[2];
  const float* b_drug    = (const float*)d_in[3];
  const float* W_target  = (const float*)d_in[4];
  const float* b_target  = (const float*)d_in[5];
  const float* W_gat     = (const float*)d_in[6];
  const float* a_src     = (const float*)d_in[7];
  const float* a_dst     = (const float*)d_in[8];
  const float* a_edge    = (const float*)d_in[9];
  const float* edge_attr = (const float*)d_in[10];
  const int*   e_dd      = (const int*)d_in[11];
  const int*   e_dt      = (const int*)d_in[12];
  const int*   e_tt      = (const int*)d_in[13];
  float* out = (float*)d_out;

  char* ws = (char*)d_ws;
  size_t off = 0;
  auto alloc = [&](size_t b) -> void* {
    void* p = ws + off;
    off += (b + 255) & ~(size_t)255;
    return p;
  };
  float* hA     = (float*)alloc((size_t)NN * DDIM * 4);
  float* hB     = (float*)alloc((size_t)NN * DDIM * 4);
  float* hp_all = (float*)alloc((size_t)NN * 3 * DDIM * 4);
  float* sbuf   = (float*)alloc((size_t)NN * 4);
  float* dbuf   = (float*)alloc((size_t)NN * 4);
  float* bias0  = (float*)alloc((size_t)NE * 4);
  float* bias1  = (float*)alloc((size_t)NE * 4);
  int* counts   = (int*)alloc((size_t)3 * NN * 4);
  int* offs0    = (int*)alloc((size_t)(NN + 1) * 4);
  int* offs1    = (int*)alloc((size_t)(NN + 1) * 4);
  int* offs2    = (int*)alloc((size_t)(NN + 1) * 4);
  int* cur0     = (int*)alloc((size_t)(NN + 1) * 4);
  int* cur1     = (int*)alloc((size_t)(NN + 1) * 4);
  int* cur2     = (int*)alloc((size_t)(NN + 1) * 4);
  int* csrc0    = (int*)alloc((size_t)NE * 4);
  int* csrc1    = (int*)alloc((size_t)NE * 4);
  int* csrc2    = (int*)alloc((size_t)NE * 4);
  int* ceid0    = (int*)alloc((size_t)NE * 4);
  short* wtd_hi = (short*)alloc((size_t)2048 * 128 * 2);
  short* wtd_lo = (short*)alloc((size_t)2048 * 128 * 2);
  short* wtt_hi = (short*)alloc((size_t)1280 * 128 * 2);
  short* wtt_lo = (short*)alloc((size_t)1280 * 128 * 2);
  short* wtg_hi = (short*)alloc((size_t)6 * 128 * 128 * 2);
  short* wtg_lo = (short*)alloc((size_t)6 * 128 * 128 * 2);

  // 0) weight prep (split + transpose)
  prep_w<<<(2048 * 128 + 255) / 256, 256, 0, stream>>>(W_drug, wtd_hi, wtd_lo, 2048);
  prep_w<<<(1280 * 128 + 255) / 256, 256, 0, stream>>>(W_target, wtt_hi, wtt_lo, 1280);
  for (int i = 0; i < 6; ++i)
    prep_w<<<(128 * 128 + 255) / 256, 256, 0, stream>>>(
        W_gat + (size_t)i * DDIM * DDIM, wtg_hi + (size_t)i * DDIM * DDIM,
        wtg_lo + (size_t)i * DDIM * DDIM, 128);

  // 1) input projections -> hA [40000,128]
  gemm_mfma<<<dim3((NDRUG + 63) / 64, 1), 256, 0, stream>>>(
      x_drug, wtd_hi, wtd_lo, b_drug, hA, NDRUG, 2048, DDIM);
  gemm_mfma<<<dim3((NTGT + 63) / 64, 1), 256, 0, stream>>>(
      x_target, wtt_hi, wtt_lo, b_target, hA + (size_t)NDRUG * DDIM, NTGT, 1280, DDIM);

  // 2) edge biases for both layers, one pass over 256MB edge_attr
  edge_bias_kernel<<<NE / 4, 256, 0, stream>>>(edge_attr, a_edge, a_edge + DDIM,
                                               bias0, bias1);
  // 3) CSR (by dst) for the 3 relations; reused by both layers
  hipMemsetAsync(counts, 0, (size_t)3 * NN * 4, stream);
  count_kernel<<<512, 256, 0, stream>>>(e_dd + NE, counts);
  count_kernel<<<512, 256, 0, stream>>>(e_dt + NE, counts + NN);
  count_kernel<<<512, 256, 0, stream>>>(e_tt + NE, counts + 2 * NN);
  scan_kernel<<<1, 1024, 0, stream>>>(counts, offs0, cur0);
  scan_kernel<<<1, 1024, 0, stream>>>(counts + NN, offs1, cur1);
  scan_kernel<<<1, 1024, 0, stream>>>(counts + 2 * NN, offs2, cur2);
  fill_kernel<<<512, 256, 0, stream>>>(e_dd, e_dd + NE, cur0, csrc0, ceid0);
  fill_kernel<<<512, 256, 0, stream>>>(e_dt, e_dt + NE, cur1, csrc1, nullptr);
  fill_kernel<<<512, 256, 0, stream>>>(e_tt, e_tt + NE, cur2, csrc2, nullptr);

  // 4) two GAT layers; per layer ONE batched GEMM over the 3 relations
  for (int l = 0; l < 2; ++l) {
    const float* hin  = (l == 0) ? hA : hB;
    float*       hout = (l == 0) ? hB : out;
    const float* lbias = (l == 0) ? bias0 : bias1;
    gemm_mfma<<<dim3(NN / 64, 3), 256, 0, stream>>>(
        hin, wtg_hi + (size_t)l * 3 * DDIM * DDIM, wtg_lo + (size_t)l * 3 * DDIM * DDIM,
        nullptr, hp_all, NN, DDIM, 3 * DDIM);
    for (int r = 0; r < 3; ++r) {
      const float* hp = hp_all + r * DDIM;
      const float* as = a_src + (size_t)(l * 3 + r) * DDIM;
      const float* ad = a_dst + (size_t)(l * 3 + r) * DDIM;
      sd_kernel<<<NN / 4, 256, 0, stream>>>(hp, 3 * DDIM, as, ad, sbuf, dbuf);
      if (r == 0)
        gat_aggregate<<<NDRUG / 4, 256, 0, stream>>>(offs0, csrc0, ceid0, lbias,
                                                     sbuf, dbuf, hp, 3 * DDIM, hout, 0, 0);
      else if (r == 1)
        gat_aggregate<<<NTGT / 4, 256, 0, stream>>>(offs1, csrc1, nullptr, nullptr,
                                                    sbuf, dbuf, hp, 3 * DDIM, hout, NDRUG, 0);
      else
        gat_aggregate<<<NTGT / 4, 256, 0, stream>>>(offs2, csrc2, nullptr, nullptr,
                                                    sbuf, dbuf, hp, 3 * DDIM, hout, NDRUG, 1);
    }
  }
}

// Round 4
// 792.336 us; speedup vs baseline: 1.5977x; 1.3011x over previous
//
#include <hip/hip_runtime.h>

#define NDRUG 20000
#define NTGT  20000
#define NN    40000
#define NE    500000
#define DDIM  128
#define CAP   256
#define NBD   313  // ceil(20000/64)

typedef __attribute__((ext_vector_type(4))) float f32x4;
typedef __attribute__((ext_vector_type(8))) short s16x8;
typedef __attribute__((ext_vector_type(4))) short s16x4;

__device__ inline unsigned short bf_rn(float x) {
  unsigned u = __float_as_uint(x);
  return (unsigned short)((u + 0x7FFFu + ((u >> 16) & 1u)) >> 16);
}
__device__ inline float bf_f(unsigned short h) {
  return __uint_as_float(((unsigned)h) << 16);
}

// ------- weight prep: W [K][128] fp32 -> Wt_hi/Wt_lo [128][K] bf16; grid.y batches -------
__global__ void prep_w(const float* __restrict__ W, short* __restrict__ hi,
                       short* __restrict__ lo, int K) {
  const size_t mat = (size_t)blockIdx.y * K * 128;
  const int idx = blockIdx.x * blockDim.x + threadIdx.x;
  if (idx >= K * 128) return;
  const int k = idx >> 7, c = idx & 127;
  const float x = W[mat + idx];
  const unsigned short h = bf_rn(x);
  hi[mat + (size_t)c * K + k] = (short)h;
  lo[mat + (size_t)c * K + k] = (short)bf_rn(x - bf_f(h));
}

// ---------------- fused input projections: both matrices in ONE launch ----------------
// blocks [0,NBD): drug (K=2048); [NBD,2*NBD): target (K=1280). BM=64,BN=128,BK=32.
__global__ __launch_bounds__(256)
void gemm_proj(const float* __restrict__ xd, const short* __restrict__ wdh,
               const short* __restrict__ wdl, const float* __restrict__ bd,
               const float* __restrict__ xt, const short* __restrict__ wth,
               const short* __restrict__ wtl, const float* __restrict__ bt,
               float* __restrict__ H) {
  __shared__ __align__(16) short Ah[64][40];
  __shared__ __align__(16) short Al[64][40];
  __shared__ __align__(16) short Bh[128][40];
  __shared__ __align__(16) short Bl[128][40];

  int b = blockIdx.x;
  const float* A; const short* WH; const short* WL; const float* bias;
  int M, K, rowbase;
  if (b < NBD) { A = xd; WH = wdh; WL = wdl; bias = bd; M = NDRUG; K = 2048; rowbase = 0; }
  else { b -= NBD; A = xt; WH = wth; WL = wtl; bias = bt; M = NTGT; K = 1280; rowbase = NDRUG; }
  const int bm = b * 64;

  const int t = threadIdx.x;
  const int wave = t >> 6, lane = t & 63;
  const int wr = (wave >> 1) * 32, wc = (wave & 1) * 64;
  const int lr = lane & 15, kg = lane >> 4;

  f32x4 acc[2][4] = {};

  for (int kk = 0; kk < K; kk += 32) {
    {
      const int r = t >> 3, k0 = (t & 7) << 2;
#pragma unroll
      for (int i = 0; i < 2; ++i) {
        const int row = r + i * 32;
        int grow = bm + row; if (grow >= M) grow = M - 1;
        const float4 v = *(const float4*)(A + (size_t)grow * K + kk + k0);
        const float xs[4] = {v.x, v.y, v.z, v.w};
        s16x4 h4, l4;
#pragma unroll
        for (int j = 0; j < 4; ++j) {
          const unsigned short hh = bf_rn(xs[j]);
          h4[j] = (short)hh;
          l4[j] = (short)bf_rn(xs[j] - bf_f(hh));
        }
        *(s16x4*)&Ah[row][k0] = h4;
        *(s16x4*)&Al[row][k0] = l4;
      }
    }
    {
      const int c = t >> 1, o = (t & 1) * 16;
      const size_t boff = (size_t)c * K + kk + o;
      *(s16x8*)&Bh[c][o]     = *(const s16x8*)(WH + boff);
      *(s16x8*)&Bh[c][o + 8] = *(const s16x8*)(WH + boff + 8);
      *(s16x8*)&Bl[c][o]     = *(const s16x8*)(WL + boff);
      *(s16x8*)&Bl[c][o + 8] = *(const s16x8*)(WL + boff + 8);
    }
    __syncthreads();

    s16x8 ah[2], al[2], bh[4], bl[4];
#pragma unroll
    for (int m = 0; m < 2; ++m) {
      ah[m] = *(const s16x8*)&Ah[wr + m * 16 + lr][kg * 8];
      al[m] = *(const s16x8*)&Al[wr + m * 16 + lr][kg * 8];
    }
#pragma unroll
    for (int n = 0; n < 4; ++n) {
      bh[n] = *(const s16x8*)&Bh[wc + n * 16 + lr][kg * 8];
      bl[n] = *(const s16x8*)&Bl[wc + n * 16 + lr][kg * 8];
    }
#pragma unroll
    for (int m = 0; m < 2; ++m)
#pragma unroll
      for (int n = 0; n < 4; ++n) {
        acc[m][n] = __builtin_amdgcn_mfma_f32_16x16x32_bf16(ah[m], bh[n], acc[m][n], 0, 0, 0);
        acc[m][n] = __builtin_amdgcn_mfma_f32_16x16x32_bf16(ah[m], bl[n], acc[m][n], 0, 0, 0);
        acc[m][n] = __builtin_amdgcn_mfma_f32_16x16x32_bf16(al[m], bh[n], acc[m][n], 0, 0, 0);
      }
    __syncthreads();
  }

#pragma unroll
  for (int n = 0; n < 4; ++n) {
    const int col = wc + n * 16 + lr;
    const float bv = bias[col];
#pragma unroll
    for (int m = 0; m < 2; ++m)
#pragma unroll
      for (int r = 0; r < 4; ++r) {
        const int row = bm + wr + m * 16 + kg * 4 + r;
        if (row < M) H[(size_t)(rowbase + row) * DDIM + col] = acc[m][n][r] + bv;
      }
  }
}

// ---------------- hp GEMM (3 relations batched) + fused s/d epilogue ----------------
// A [NN,128]; Wt6 = 3 relation weights; C [NN,384]; s_all/d_all [3][NN].
__global__ __launch_bounds__(256)
void gemm_gat(const float* __restrict__ A, const short* __restrict__ WtH6,
              const short* __restrict__ WtL6, const float* __restrict__ asrc_l,
              const float* __restrict__ adst_l, float* __restrict__ C,
              float* __restrict__ s_all, float* __restrict__ d_all) {
  const int rel = blockIdx.y;
  const short* WtH = WtH6 + (size_t)rel * 128 * 128;
  const short* WtL = WtL6 + (size_t)rel * 128 * 128;

  __shared__ __align__(16) short Ah[64][40];
  __shared__ __align__(16) short Al[64][40];
  __shared__ __align__(16) short Bh[128][40];
  __shared__ __align__(16) short Bl[128][40];
  __shared__ float sred[2][64], dred[2][64];

  const int t = threadIdx.x;
  const int bm = blockIdx.x * 64;
  const int wave = t >> 6, lane = t & 63;
  const int wr = (wave >> 1) * 32, wc = (wave & 1) * 64;
  const int lr = lane & 15, kg = lane >> 4;

  f32x4 acc[2][4] = {};

  for (int kk = 0; kk < 128; kk += 32) {
    {
      const int r = t >> 3, k0 = (t & 7) << 2;
#pragma unroll
      for (int i = 0; i < 2; ++i) {
        const int row = r + i * 32;
        const float4 v = *(const float4*)(A + (size_t)(bm + row) * DDIM + kk + k0);
        const float xs[4] = {v.x, v.y, v.z, v.w};
        s16x4 h4, l4;
#pragma unroll
        for (int j = 0; j < 4; ++j) {
          const unsigned short hh = bf_rn(xs[j]);
          h4[j] = (short)hh;
          l4[j] = (short)bf_rn(xs[j] - bf_f(hh));
        }
        *(s16x4*)&Ah[row][k0] = h4;
        *(s16x4*)&Al[row][k0] = l4;
      }
    }
    {
      const int c = t >> 1, o = (t & 1) * 16;
      const size_t boff = (size_t)c * 128 + kk + o;
      *(s16x8*)&Bh[c][o]     = *(const s16x8*)(WtH + boff);
      *(s16x8*)&Bh[c][o + 8] = *(const s16x8*)(WtH + boff + 8);
      *(s16x8*)&Bl[c][o]     = *(const s16x8*)(WtL + boff);
      *(s16x8*)&Bl[c][o + 8] = *(const s16x8*)(WtL + boff + 8);
    }
    __syncthreads();

    s16x8 ah[2], al[2], bh[4], bl[4];
#pragma unroll
    for (int m = 0; m < 2; ++m) {
      ah[m] = *(const s16x8*)&Ah[wr + m * 16 + lr][kg * 8];
      al[m] = *(const s16x8*)&Al[wr + m * 16 + lr][kg * 8];
    }
#pragma unroll
    for (int n = 0; n < 4; ++n) {
      bh[n] = *(const s16x8*)&Bh[wc + n * 16 + lr][kg * 8];
      bl[n] = *(const s16x8*)&Bl[wc + n * 16 + lr][kg * 8];
    }
#pragma unroll
    for (int m = 0; m < 2; ++m)
#pragma unroll
      for (int n = 0; n < 4; ++n) {
        acc[m][n] = __builtin_amdgcn_mfma_f32_16x16x32_bf16(ah[m], bh[n], acc[m][n], 0, 0, 0);
        acc[m][n] = __builtin_amdgcn_mfma_f32_16x16x32_bf16(ah[m], bl[n], acc[m][n], 0, 0, 0);
        acc[m][n] = __builtin_amdgcn_mfma_f32_16x16x32_bf16(al[m], bh[n], acc[m][n], 0, 0, 0);
      }
    __syncthreads();
  }

  // epilogue: C write + fused s/d ---------------------------------------
  const float* as = asrc_l + rel * DDIM;
  const float* ad = adst_l + rel * DDIM;
  float asv[4], adv[4];
#pragma unroll
  for (int n = 0; n < 4; ++n) {
    asv[n] = as[wc + n * 16 + lr];
    adv[n] = ad[wc + n * 16 + lr];
  }
#pragma unroll
  for (int n = 0; n < 4; ++n) {
    const int col = rel * 128 + wc + n * 16 + lr;
#pragma unroll
    for (int m = 0; m < 2; ++m)
#pragma unroll
      for (int r = 0; r < 4; ++r) {
        const int row = bm + wr + m * 16 + kg * 4 + r;
        C[(size_t)row * 384 + col] = acc[m][n][r];
      }
  }
#pragma unroll
  for (int m = 0; m < 2; ++m)
#pragma unroll
    for (int r = 0; r < 4; ++r) {
      float ps = 0.f, pd = 0.f;
#pragma unroll
      for (int n = 0; n < 4; ++n) {
        ps += acc[m][n][r] * asv[n];
        pd += acc[m][n][r] * adv[n];
      }
#pragma unroll
      for (int o = 1; o < 16; o <<= 1) {
        ps += __shfl_xor(ps, o);
        pd += __shfl_xor(pd, o);
      }
      if (lr == 0) {
        const int lrow = wr + m * 16 + kg * 4 + r;
        sred[wc >> 6][lrow] = ps;
        dred[wc >> 6][lrow] = pd;
      }
    }
  __syncthreads();
  if (t < 64) {
    s_all[rel * NN + bm + t] = sred[0][t] + sred[1][t];
    d_all[rel * NN + bm + t] = dred[0][t] + dred[1][t];
  }
}

// ------------- edge bias for BOTH layers, float2 loads -------------
__global__ __launch_bounds__(256)
void edge_bias_kernel(const float* __restrict__ ea, const float* __restrict__ ae0,
                      const float* __restrict__ ae1, float* __restrict__ b0,
                      float* __restrict__ b1) {
  const int wave = threadIdx.x >> 6, lane = threadIdx.x & 63;
  const int e = blockIdx.x * 4 + wave;
  if (e >= NE) return;
  const float2 v = *(const float2*)(ea + (size_t)e * DDIM + (lane << 1));
  float s0 = v.x * ae0[lane << 1] + v.y * ae0[(lane << 1) + 1];
  float s1 = v.x * ae1[lane << 1] + v.y * ae1[(lane << 1) + 1];
#pragma unroll
  for (int o = 32; o; o >>= 1) { s0 += __shfl_xor(s0, o); s1 += __shfl_xor(s1, o); }
  if (lane == 0) { b0[e] = s0; b1[e] = s1; }
}

// ------------- CSR build (3 relations batched) -------------
__global__ void count3(const int* __restrict__ d0, const int* __restrict__ d1,
                       const int* __restrict__ d2, int* __restrict__ counts) {
  const int rel = blockIdx.y;
  const int* dst = rel == 0 ? d0 : (rel == 1 ? d1 : d2);
  int* c = counts + rel * NN;
  for (int e = blockIdx.x * blockDim.x + threadIdx.x; e < NE; e += gridDim.x * blockDim.x)
    atomicAdd(&c[dst[e]], 1);
}

__global__ __launch_bounds__(1024)
void scan3(const int* __restrict__ counts_all, int* __restrict__ offs_all,
           int* __restrict__ cursor_all) {
  const int rel = blockIdx.x;
  const int* counts = counts_all + rel * NN;
  int* offs = offs_all + rel * (NN + 1);
  int* cursor = cursor_all + rel * (NN + 1);
  __shared__ int part[1024];
  const int t = threadIdx.x;
  const int CH = 40;
  const int base = t * CH;
  const int lim = min(base + CH, NN);
  int sum = 0;
  for (int i = base; i < lim; ++i) sum += counts[i];
  part[t] = sum;
  __syncthreads();
  for (int o = 1; o < 1024; o <<= 1) {
    const int v = (t >= o) ? part[t - o] : 0;
    __syncthreads();
    part[t] += v;
    __syncthreads();
  }
  int run = (t == 0) ? 0 : part[t - 1];
  for (int i = base; i < lim; ++i) { offs[i] = run; cursor[i] = run; run += counts[i]; }
  if (t == 1023) offs[NN] = part[1023];
}

__global__ void fill3(const int* __restrict__ s0, const int* __restrict__ d0,
                      const int* __restrict__ s1, const int* __restrict__ d1,
                      const int* __restrict__ s2, const int* __restrict__ d2,
                      int* __restrict__ cursor_all, int* __restrict__ csrc_all,
                      int* __restrict__ ceid0) {
  const int rel = blockIdx.y;
  const int* src = rel == 0 ? s0 : (rel == 1 ? s1 : s2);
  const int* dst = rel == 0 ? d0 : (rel == 1 ? d1 : d2);
  int* cursor = cursor_all + rel * (NN + 1);
  int* csrc = csrc_all + (size_t)rel * NE;
  for (int e = blockIdx.x * blockDim.x + threadIdx.x; e < NE; e += gridDim.x * blockDim.x) {
    const int p = atomicAdd(&cursor[dst[e]], 1);
    csrc[p] = src[e];
    if (rel == 0) ceid0[p] = e;
  }
}

// ------------- softmax-gather core (per wave, one node, one relation) -------------
__device__ __forceinline__ void gat_one(const int* __restrict__ offs,
                                        const int* __restrict__ csrc,
                                        const int* __restrict__ ceid,
                                        const float* __restrict__ ebias,
                                        const float* __restrict__ s, float dn,
                                        const float* __restrict__ hpr, int node,
                                        float* exbuf, int* srcbuf, int lane,
                                        int c0, int c1, float& o0, float& o1) {
  const int beg = offs[node];
  int cnt = offs[node + 1] - beg;
  if (cnt > CAP) cnt = CAP;
  if (cnt == 0) return;
  __threadfence_block();  // order LDS reuse across calls
  float m = -1e30f;
  for (int i = lane; i < cnt; i += 64) {
    const int sn = csrc[beg + i];
    float logit = s[sn] + dn;
    if (ebias) logit += ebias[ceid[beg + i]];
    const float e = logit >= 0.f ? logit : 0.2f * logit;
    exbuf[i] = e;
    srcbuf[i] = sn;
    m = fmaxf(m, e);
  }
#pragma unroll
  for (int o = 32; o; o >>= 1) m = fmaxf(m, __shfl_xor(m, o));
  float ssum = 0.f;
  for (int i = lane; i < cnt; i += 64) {
    const float ex = __expf(exbuf[i] - m);
    exbuf[i] = ex;
    ssum += ex;
  }
#pragma unroll
  for (int o = 32; o; o >>= 1) ssum += __shfl_xor(ssum, o);
  const float inv = 1.f / (ssum + 1e-16f);
  __threadfence_block();
  float n0 = 0.f, n1 = 0.f;
  int i = 0;
  for (; i + 4 <= cnt; i += 4) {
    const float w0 = exbuf[i], w1 = exbuf[i + 1], w2 = exbuf[i + 2], w3 = exbuf[i + 3];
    const float* h0 = hpr + (size_t)srcbuf[i] * 384;
    const float* h1 = hpr + (size_t)srcbuf[i + 1] * 384;
    const float* h2 = hpr + (size_t)srcbuf[i + 2] * 384;
    const float* h3 = hpr + (size_t)srcbuf[i + 3] * 384;
    n0 += w0 * h0[c0] + w1 * h1[c0] + w2 * h2[c0] + w3 * h3[c0];
    n1 += w0 * h0[c1] + w1 * h1[c1] + w2 * h2[c1] + w3 * h3[c1];
  }
  for (; i < cnt; ++i) {
    const float w = exbuf[i];
    const float* hr = hpr + (size_t)srcbuf[i] * 384;
    n0 += w * hr[c0];
    n1 += w * hr[c1];
  }
  float v0 = n0 * inv, v1 = n1 * inv;
  o0 += (v0 > 0.f ? v0 : expm1f(v0));
  o1 += (v1 > 0.f ? v1 : expm1f(v1));
}

// ------------- drug rows: dd relation only -------------
__global__ __launch_bounds__(256)
void agg_drug(const int* __restrict__ offs_all, const int* __restrict__ csrc_all,
              const int* __restrict__ ceid0, const float* __restrict__ ebias,
              const float* __restrict__ s_all, const float* __restrict__ d_all,
              const float* __restrict__ hp, float* __restrict__ outp) {
  __shared__ float exbuf[4][CAP];
  __shared__ int   srcbuf[4][CAP];
  const int wave = threadIdx.x >> 6, lane = threadIdx.x & 63;
  const int node = blockIdx.x * 4 + wave;
  const int c0 = lane, c1 = lane + 64;
  float o0 = 0.f, o1 = 0.f;
  gat_one(offs_all, csrc_all, ceid0, ebias, s_all, d_all[node], hp, node,
          exbuf[wave], srcbuf[wave], lane, c0, c1, o0, o1);
  float* orow = outp + (size_t)node * DDIM;
  orow[c0] = o0 * (1.f / 3.f);
  orow[c1] = o1 * (1.f / 3.f);
}

// ------------- target rows: dt + tt relations, single write -------------
__global__ __launch_bounds__(256)
void agg_tgt(const int* __restrict__ offs_all, const int* __restrict__ csrc_all,
             const float* __restrict__ s_all, const float* __restrict__ d_all,
             const float* __restrict__ hp, float* __restrict__ outp) {
  __shared__ float exbuf[4][CAP];
  __shared__ int   srcbuf[4][CAP];
  const int wave = threadIdx.x >> 6, lane = threadIdx.x & 63;
  const int node = NDRUG + blockIdx.x * 4 + wave;
  const int c0 = lane, c1 = lane + 64;
  float o0 = 0.f, o1 = 0.f;
#pragma unroll
  for (int rel = 1; rel <= 2; ++rel) {
    gat_one(offs_all + rel * (NN + 1), csrc_all + (size_t)rel * NE, nullptr, nullptr,
            s_all + rel * NN, d_all[rel * NN + node], hp + rel * DDIM, node,
            exbuf[wave], srcbuf[wave], lane, c0, c1, o0, o1);
  }
  float* orow = outp + (size_t)node * DDIM;
  orow[c0] = o0 * (1.f / 3.f);
  orow[c1] = o1 * (1.f / 3.f);
}

extern "C" void kernel_launch(void* const* d_in, const int* in_sizes, int n_in,
                              void* d_out, int out_size, void* d_ws, size_t ws_size,
                              hipStream_t stream) {
  const float* x_drug    = (const float*)d_in[0];
  const float* x_target  = (const float*)d_in[1];
  const float* W_drug    = (const float*)d_in[2];
  const float* b_drug    = (const float*)d_in[3];
  const float* W_target  = (const float*)d_in[4];
  const float* b_target  = (const float*)d_in[5];
  const float* W_gat     = (const float*)d_in[6];
  const float* a_src     = (const float*)d_in[7];
  const float* a_dst     = (const float*)d_in[8];
  const float* a_edge    = (const float*)d_in[9];
  const float* edge_attr = (const float*)d_in[10];
  const int*   e_dd      = (const int*)d_in[11];
  const int*   e_dt      = (const int*)d_in[12];
  const int*   e_tt      = (const int*)d_in[13];
  float* out = (float*)d_out;

  char* ws = (char*)d_ws;
  size_t off = 0;
  auto alloc = [&](size_t b) -> void* {
    void* p = ws + off;
    off += (b + 255) & ~(size_t)255;
    return p;
  };
  float* hA     = (float*)alloc((size_t)NN * DDIM * 4);
  float* hB     = (float*)alloc((size_t)NN * DDIM * 4);
  float* hp_all = (float*)alloc((size_t)NN * 3 * DDIM * 4);
  float* s_all  = (float*)alloc((size_t)3 * NN * 4);
  float* d_allb = (float*)alloc((size_t)3 * NN * 4);
  float* bias0  = (float*)alloc((size_t)NE * 4);
  float* bias1  = (float*)alloc((size_t)NE * 4);
  int* counts   = (int*)alloc((size_t)3 * NN * 4);
  int* offs_all = (int*)alloc((size_t)3 * (NN + 1) * 4);
  int* cur_all  = (int*)alloc((size_t)3 * (NN + 1) * 4);
  int* csrc_all = (int*)alloc((size_t)3 * NE * 4);
  int* ceid0    = (int*)alloc((size_t)NE * 4);
  short* wtd_hi = (short*)alloc((size_t)2048 * 128 * 2);
  short* wtd_lo = (short*)alloc((size_t)2048 * 128 * 2);
  short* wtt_hi = (short*)alloc((size_t)1280 * 128 * 2);
  short* wtt_lo = (short*)alloc((size_t)1280 * 128 * 2);
  short* wtg_hi = (short*)alloc((size_t)6 * 128 * 128 * 2);
  short* wtg_lo = (short*)alloc((size_t)6 * 128 * 128 * 2);

  // 0) weight prep
  prep_w<<<dim3((2048 * 128 + 255) / 256, 1), 256, 0, stream>>>(W_drug, wtd_hi, wtd_lo, 2048);
  prep_w<<<dim3((1280 * 128 + 255) / 256, 1), 256, 0, stream>>>(W_target, wtt_hi, wtt_lo, 1280);
  prep_w<<<dim3((128 * 128 + 255) / 256, 6), 256, 0, stream>>>(W_gat, wtg_hi, wtg_lo, 128);

  // 1) both projections in one launch -> hA [40000,128]
  gemm_proj<<<2 * NBD, 256, 0, stream>>>(x_drug, wtd_hi, wtd_lo, b_drug,
                                         x_target, wtt_hi, wtt_lo, b_target, hA);

  // 2) edge biases for both layers (one 256MB pass)
  edge_bias_kernel<<<NE / 4, 256, 0, stream>>>(edge_attr, a_edge, a_edge + DDIM,
                                               bias0, bias1);
  // 3) CSR build (3 relations, reused by both layers)
  hipMemsetAsync(counts, 0, (size_t)3 * NN * 4, stream);
  count3<<<dim3(170, 3), 256, 0, stream>>>(e_dd + NE, e_dt + NE, e_tt + NE, counts);
  scan3<<<3, 1024, 0, stream>>>(counts, offs_all, cur_all);
  fill3<<<dim3(170, 3), 256, 0, stream>>>(e_dd, e_dd + NE, e_dt, e_dt + NE,
                                          e_tt, e_tt + NE, cur_all, csrc_all, ceid0);

  // 4) two GAT layers
  for (int l = 0; l < 2; ++l) {
    const float* hin  = (l == 0) ? hA : hB;
    float*       hout = (l == 0) ? hB : out;
    const float* lbias = (l == 0) ? bias0 : bias1;
    gemm_gat<<<dim3(NN / 64, 3), 256, 0, stream>>>(
        hin, wtg_hi + (size_t)l * 3 * DDIM * DDIM, wtg_lo + (size_t)l * 3 * DDIM * DDIM,
        a_src + (size_t)l * 3 * DDIM, a_dst + (size_t)l * 3 * DDIM,
        hp_all, s_all, d_allb);
    agg_drug<<<NDRUG / 4, 256, 0, stream>>>(offs_all, csrc_all, ceid0, lbias,
                                            s_all, d_allb, hp_all, hout);
    agg_tgt<<<NTGT / 4, 256, 0, stream>>>(offs_all, csrc_all, s_all, d_allb,
                                          hp_all, hout);
  }
}